// Round 1
// baseline (439.676 us; speedup 1.0000x reference)
//
#include <hip/hip_runtime.h>

// Overlaps: out[i,j] = IoU(boxes0[i], boxes1[j]) if labels match && batches match else 0
// N0=N1=10000 -> 1e8 float32 outputs = 400 MB write-dominated.

__global__ __launch_bounds__(256) void overlaps_kernel(
    const float4* __restrict__ boxes0,   // [n0] xyxy
    const int*    __restrict__ labels0,  // [n0]
    const int*    __restrict__ batches0, // [n0]
    const float4* __restrict__ boxes1,   // [n1] xyxy
    const int*    __restrict__ labels1,  // [n1]
    const int*    __restrict__ batches1, // [n1]
    float*        __restrict__ out,      // [n0, n1]
    int n0, int n1)
{
    const int row = blockIdx.y;
    if (row >= n0) return;

    // Block-uniform row data -> scalar loads
    const float4 b0 = boxes0[row];
    const int    l0 = labels0[row];
    const int    t0 = batches0[row];
    const float  area0 = (b0.z - b0.x) * (b0.w - b0.y);

    const int j4 = (blockIdx.x * blockDim.x + threadIdx.x) * 4;
    if (j4 >= n1) return;

    if (j4 + 3 < n1) {
        // Vector path: 4 consecutive columns, one float4 store.
        const int4 l1 = *reinterpret_cast<const int4*>(labels1 + j4);
        const int4 t1 = *reinterpret_cast<const int4*>(batches1 + j4);

        float4 res;
        float* r = &res.x;
        const int* lp = &l1.x;
        const int* tp = &t1.x;

        #pragma unroll
        for (int k = 0; k < 4; ++k) {
            float v = 0.0f;
            if (lp[k] == l0 && tp[k] == t0) {
                const float4 b1 = boxes1[j4 + k];
                const float x1 = fmaxf(b0.x, b1.x);
                const float y1 = fmaxf(b0.y, b1.y);
                const float x2 = fminf(b0.z, b1.z);
                const float y2 = fminf(b0.w, b1.w);
                const float inter = fmaxf(x2 - x1, 0.0f) * fmaxf(y2 - y1, 0.0f);
                const float area1 = (b1.z - b1.x) * (b1.w - b1.y);
                const float uni = area0 + area1 - inter;
                v = (uni > 0.0f) ? (inter / uni) : 0.0f;
            }
            r[k] = v;
        }
        *reinterpret_cast<float4*>(out + (size_t)row * n1 + j4) = res;
    } else {
        // Scalar tail (n1 not a multiple of 4)
        for (int j = j4; j < n1; ++j) {
            float v = 0.0f;
            if (labels1[j] == l0 && batches1[j] == t0) {
                const float4 b1 = boxes1[j];
                const float x1 = fmaxf(b0.x, b1.x);
                const float y1 = fmaxf(b0.y, b1.y);
                const float x2 = fminf(b0.z, b1.z);
                const float y2 = fminf(b0.w, b1.w);
                const float inter = fmaxf(x2 - x1, 0.0f) * fmaxf(y2 - y1, 0.0f);
                const float area1 = (b1.z - b1.x) * (b1.w - b1.y);
                const float uni = area0 + area1 - inter;
                v = (uni > 0.0f) ? (inter / uni) : 0.0f;
            }
            out[(size_t)row * n1 + j] = v;
        }
    }
}

extern "C" void kernel_launch(void* const* d_in, const int* in_sizes, int n_in,
                              void* d_out, int out_size, void* d_ws, size_t ws_size,
                              hipStream_t stream) {
    const float4* boxes0   = (const float4*)d_in[0];
    const int*    labels0  = (const int*)   d_in[1];
    const int*    batches0 = (const int*)   d_in[2];
    const float4* boxes1   = (const float4*)d_in[3];
    const int*    labels1  = (const int*)   d_in[4];
    const int*    batches1 = (const int*)   d_in[5];
    float*        out      = (float*)d_out;

    const int n0 = in_sizes[1];  // labels0 count
    const int n1 = in_sizes[4];  // labels1 count

    const int block = 256;
    const int cols_per_block = block * 4;                 // 1024 columns per block
    const int gx = (n1 + cols_per_block - 1) / cols_per_block;
    dim3 grid(gx, n0);

    overlaps_kernel<<<grid, block, 0, stream>>>(
        boxes0, labels0, batches0, boxes1, labels1, batches1, out, n0, n1);
}

// Round 2
// 417.133 us; speedup vs baseline: 1.0540x; 1.0540x over previous
//
#include <hip/hip_runtime.h>

// Overlaps: out[i,j] = IoU(boxes0[i], boxes1[j]) * (key0[i]==key1[j])
// 1e8 fp32 outputs = 400 MB -> write-BW bound, floor ~63 us @ 6.3 TB/s.
// Strategy: 8 rows x 4 cols per thread (8 float4 stores/thread) to amortize
// wave prologue; branchless key-select; packed key precomputed into d_ws.

constexpr int ROWS_PER_BLOCK = 8;

__global__ __launch_bounds__(256) void make_keys(
    const int* __restrict__ labels0, const int* __restrict__ batches0, int n0,
    const int* __restrict__ labels1, const int* __restrict__ batches1, int n1,
    int* __restrict__ key0, int* __restrict__ key1)
{
    const int i = blockIdx.x * blockDim.x + threadIdx.x;
    if (i < n0) key0[i] = (batches0[i] << 16) | (labels0[i] & 0xFFFF);
    if (i < n1) key1[i] = (batches1[i] << 16) | (labels1[i] & 0xFFFF);
}

__global__ __launch_bounds__(256) void overlaps_kernel(
    const float4* __restrict__ boxes0,   // [n0] xyxy
    const int*    __restrict__ key0,     // [n0] packed batch|label
    const float4* __restrict__ boxes1,   // [n1]
    const int*    __restrict__ key1,     // [n1]
    float*        __restrict__ out,      // [n0, n1]
    int n0, int n1)
{
    const int r0 = blockIdx.y * ROWS_PER_BLOCK;
    const int j4 = (blockIdx.x * 256 + threadIdx.x) * 4;
    if (j4 >= n1) return;

    const bool vec = (j4 + 3 < n1);

    // Column-side data: loaded once, reused for all ROWS_PER_BLOCK rows.
    int4   k1v = make_int4(0, 0, 0, 0);
    float4 b1[4];
    if (vec) {
        k1v = *reinterpret_cast<const int4*>(key1 + j4);
        #pragma unroll
        for (int k = 0; k < 4; ++k) b1[k] = boxes1[j4 + k];
    }

    float* orow = out + (size_t)r0 * n1 + j4;

    #pragma unroll
    for (int r = 0; r < ROWS_PER_BLOCK; ++r) {
        const int row = r0 + r;
        if (row >= n0) return;

        // Block-uniform -> scalar loads
        const float4 b0 = boxes0[row];
        const int    k0 = key0[row];
        const float  area0 = (b0.z - b0.x) * (b0.w - b0.y);

        if (vec) {
            float4 res;
            float*     rp = &res.x;
            const int* kp = &k1v.x;
            #pragma unroll
            for (int k = 0; k < 4; ++k) {
                const float x1 = fmaxf(b0.x, b1[k].x);
                const float y1 = fmaxf(b0.y, b1[k].y);
                const float x2 = fminf(b0.z, b1[k].z);
                const float y2 = fminf(b0.w, b1[k].w);
                const float inter = fmaxf(x2 - x1, 0.0f) * fmaxf(y2 - y1, 0.0f);
                const float area1 = (b1[k].z - b1[k].x) * (b1[k].w - b1[k].y);
                const float uni = area0 + area1 - inter;
                float v = inter * __builtin_amdgcn_rcpf(uni);
                v = (uni > 0.0f) ? v : 0.0f;
                rp[k] = (kp[k] == k0) ? v : 0.0f;
            }
            *reinterpret_cast<float4*>(orow) = res;
        } else {
            for (int j = j4; j < n1; ++j) {
                float v = 0.0f;
                if (key1[j] == k0) {
                    const float4 bb = boxes1[j];
                    const float x1 = fmaxf(b0.x, bb.x);
                    const float y1 = fmaxf(b0.y, bb.y);
                    const float x2 = fminf(b0.z, bb.z);
                    const float y2 = fminf(b0.w, bb.w);
                    const float inter = fmaxf(x2 - x1, 0.0f) * fmaxf(y2 - y1, 0.0f);
                    const float area1 = (bb.z - bb.x) * (bb.w - bb.y);
                    const float uni = area0 + area1 - inter;
                    v = (uni > 0.0f) ? (inter / uni) : 0.0f;
                }
                out[(size_t)row * n1 + j] = v;
            }
        }
        orow += n1;
    }
}

extern "C" void kernel_launch(void* const* d_in, const int* in_sizes, int n_in,
                              void* d_out, int out_size, void* d_ws, size_t ws_size,
                              hipStream_t stream) {
    const float4* boxes0   = (const float4*)d_in[0];
    const int*    labels0  = (const int*)   d_in[1];
    const int*    batches0 = (const int*)   d_in[2];
    const float4* boxes1   = (const float4*)d_in[3];
    const int*    labels1  = (const int*)   d_in[4];
    const int*    batches1 = (const int*)   d_in[5];
    float*        out      = (float*)d_out;

    const int n0 = in_sizes[1];
    const int n1 = in_sizes[4];

    int* key0 = (int*)d_ws;
    int* key1 = key0 + ((n0 + 3) & ~3);

    const int nmax = (n0 > n1) ? n0 : n1;
    make_keys<<<(nmax + 255) / 256, 256, 0, stream>>>(
        labels0, batches0, n0, labels1, batches1, n1, key0, key1);

    const int cols_per_block = 256 * 4;  // 1024
    const int gx = (n1 + cols_per_block - 1) / cols_per_block;
    const int gy = (n0 + ROWS_PER_BLOCK - 1) / ROWS_PER_BLOCK;
    dim3 grid(gx, gy);

    overlaps_kernel<<<grid, 256, 0, stream>>>(
        boxes0, key0, boxes1, key1, out, n0, n1);
}